// Round 1
// baseline (616.615 us; speedup 1.0000x reference)
//
#include <hip/hip_runtime.h>

typedef __bf16 bf16_t;
typedef bf16_t bf16x8 __attribute__((ext_vector_type(8)));
typedef bf16_t bf16x4 __attribute__((ext_vector_type(4)));
typedef float f32x4 __attribute__((ext_vector_type(4)));

#define N_NODES 8192
#define DIM 512

// ---- transpose + convert: x [8192,512] f32 -> xT [512,8192] bf16 ------------
__global__ __launch_bounds__(256) void k_transpose_x(const float* __restrict__ x,
                                                     bf16_t* __restrict__ xT) {
  __shared__ float tile[64][65];
  const int m0 = blockIdx.x * 64;
  const int n0 = blockIdx.y * 64;
  const int t = threadIdx.x;
  const int r = t >> 4;         // 0..15
  const int c = (t & 15) << 2;  // 0..60
#pragma unroll
  for (int i = 0; i < 4; ++i) {
    f32x4 v = *(const f32x4*)&x[(size_t)(m0 + r + i * 16) * DIM + n0 + c];
    tile[r + i * 16][c + 0] = v.x;
    tile[r + i * 16][c + 1] = v.y;
    tile[r + i * 16][c + 2] = v.z;
    tile[r + i * 16][c + 3] = v.w;
  }
  __syncthreads();
#pragma unroll
  for (int i = 0; i < 4; ++i) {
    const int rn = r + i * 16;
    bf16x4 o = {(bf16_t)tile[c + 0][rn], (bf16_t)tile[c + 1][rn],
                (bf16_t)tile[c + 2][rn], (bf16_t)tile[c + 3][rn]};
    *(bf16x4*)&xT[(size_t)(n0 + rn) * N_NODES + m0 + c] = o;
  }
}

// ---- convert W [512,512] f32 -> bf16 (layout already [n][k] for B^T) --------
__global__ __launch_bounds__(256) void k_cvt_w(const float* __restrict__ W,
                                               bf16_t* __restrict__ Wb) {
  const int t = blockIdx.x * 256 + threadIdx.x;  // 65536 threads, 4 elems each
  f32x4 v = *(const f32x4*)&W[(size_t)t * 4];
  bf16x4 o = {(bf16_t)v.x, (bf16_t)v.y, (bf16_t)v.z, (bf16_t)v.w};
  *(bf16x4*)&Wb[(size_t)t * 4] = o;
}

// ---- GEMM1: agg = adj(f32, cvt on the fly) @ x  -> agg bf16 [8192,512] ------
// 128x128 tile, BK=32, 512 threads = 8 waves (2 row x 4 col), wave = 64x32.
__global__ __launch_bounds__(512) void k_gemm1(const float* __restrict__ A,    // adj [8192,8192]
                                               const bf16_t* __restrict__ Bt,  // xT  [512,8192]
                                               bf16_t* __restrict__ C) {       // agg [8192,512]
  constexpr int K = N_NODES;
  constexpr int LDK = 40;  // pad 32 -> 40 elements to spread LDS banks
  __shared__ bf16_t As[128 * LDK];
  __shared__ bf16_t Bs[128 * LDK];
  const int m0 = blockIdx.y * 128;
  const int n0 = blockIdx.x * 128;
  const int t = threadIdx.x;
  const int lane = t & 63;
  const int w = t >> 6;   // 0..7
  const int wr = w & 1;   // wave row (64 rows each)
  const int wc = w >> 1;  // wave col (32 cols each)
  const int lrow = lane & 15;
  const int quad = lane >> 4;
  const int sr = t >> 2;  // staging row 0..127
  const int sq = t & 3;   // staging quarter (8 elems)

  const float* ap = A + (size_t)(m0 + sr) * K + sq * 8;
  const bf16_t* bp = Bt + (size_t)(n0 + sr) * K + sq * 8;
  bf16_t* aw = &As[sr * LDK + sq * 8];
  bf16_t* bw = &Bs[sr * LDK + sq * 8];

  f32x4 acc[4][2] = {};

  for (int k0 = 0; k0 < K; k0 += 32) {
    f32x4 a0 = *(const f32x4*)(ap + k0);
    f32x4 a1 = *(const f32x4*)(ap + k0 + 4);
    bf16x8 bv = *(const bf16x8*)(bp + k0);
    bf16x8 av = {(bf16_t)a0.x, (bf16_t)a0.y, (bf16_t)a0.z, (bf16_t)a0.w,
                 (bf16_t)a1.x, (bf16_t)a1.y, (bf16_t)a1.z, (bf16_t)a1.w};
    *(bf16x8*)aw = av;
    *(bf16x8*)bw = bv;
    __syncthreads();
    bf16x8 af[4], bfv[2];
#pragma unroll
    for (int i = 0; i < 4; ++i)
      af[i] = *(const bf16x8*)&As[(wr * 64 + i * 16 + lrow) * LDK + quad * 8];
#pragma unroll
    for (int j = 0; j < 2; ++j)
      bfv[j] = *(const bf16x8*)&Bs[(wc * 32 + j * 16 + lrow) * LDK + quad * 8];
#pragma unroll
    for (int i = 0; i < 4; ++i)
#pragma unroll
      for (int j = 0; j < 2; ++j)
        acc[i][j] = __builtin_amdgcn_mfma_f32_16x16x32_bf16(af[i], bfv[j], acc[i][j], 0, 0, 0);
    __syncthreads();
  }

#pragma unroll
  for (int i = 0; i < 4; ++i)
#pragma unroll
    for (int j = 0; j < 2; ++j) {
      const int col = n0 + wc * 32 + j * 16 + lrow;
#pragma unroll
      for (int r = 0; r < 4; ++r) {
        const int row = m0 + wr * 64 + i * 16 + quad * 4 + r;
        C[(size_t)row * DIM + col] = (bf16_t)acc[i][j][r];
      }
    }
}

// ---- GEMM2: out = relu(agg @ W^T + b), fp32 out -----------------------------
__global__ __launch_bounds__(512) void k_gemm2(const bf16_t* __restrict__ A,   // agg [8192,512]
                                               const bf16_t* __restrict__ Bw,  // Wb  [512,512]
                                               const float* __restrict__ bias,
                                               float* __restrict__ out) {
  constexpr int K = DIM;
  constexpr int LDK = 40;
  __shared__ bf16_t As[128 * LDK];
  __shared__ bf16_t Bs[128 * LDK];
  const int m0 = blockIdx.y * 128;
  const int n0 = blockIdx.x * 128;
  const int t = threadIdx.x;
  const int lane = t & 63;
  const int w = t >> 6;
  const int wr = w & 1;
  const int wc = w >> 1;
  const int lrow = lane & 15;
  const int quad = lane >> 4;
  const int sr = t >> 2;
  const int sq = t & 3;

  const bf16_t* ap = A + (size_t)(m0 + sr) * K + sq * 8;
  const bf16_t* bp = Bw + (size_t)(n0 + sr) * K + sq * 8;
  bf16_t* aw = &As[sr * LDK + sq * 8];
  bf16_t* bw = &Bs[sr * LDK + sq * 8];

  f32x4 acc[4][2] = {};

  for (int k0 = 0; k0 < K; k0 += 32) {
    bf16x8 av = *(const bf16x8*)(ap + k0);
    bf16x8 bv = *(const bf16x8*)(bp + k0);
    *(bf16x8*)aw = av;
    *(bf16x8*)bw = bv;
    __syncthreads();
    bf16x8 af[4], bfv[2];
#pragma unroll
    for (int i = 0; i < 4; ++i)
      af[i] = *(const bf16x8*)&As[(wr * 64 + i * 16 + lrow) * LDK + quad * 8];
#pragma unroll
    for (int j = 0; j < 2; ++j)
      bfv[j] = *(const bf16x8*)&Bs[(wc * 32 + j * 16 + lrow) * LDK + quad * 8];
#pragma unroll
    for (int i = 0; i < 4; ++i)
#pragma unroll
      for (int j = 0; j < 2; ++j)
        acc[i][j] = __builtin_amdgcn_mfma_f32_16x16x32_bf16(af[i], bfv[j], acc[i][j], 0, 0, 0);
    __syncthreads();
  }

#pragma unroll
  for (int i = 0; i < 4; ++i)
#pragma unroll
    for (int j = 0; j < 2; ++j) {
      const int col = n0 + wc * 32 + j * 16 + lrow;
      const float bj = bias[col];
#pragma unroll
      for (int r = 0; r < 4; ++r) {
        const int row = m0 + wr * 64 + i * 16 + quad * 4 + r;
        float v = acc[i][j][r] + bj;
        out[(size_t)row * DIM + col] = v > 0.0f ? v : 0.0f;
      }
    }
}

extern "C" void kernel_launch(void* const* d_in, const int* in_sizes, int n_in,
                              void* d_out, int out_size, void* d_ws, size_t ws_size,
                              hipStream_t stream) {
  const float* x = (const float*)d_in[0];    // [8192,512]
  const float* adj = (const float*)d_in[1];  // [8192,8192]
  const float* W = (const float*)d_in[2];    // [512,512]
  const float* b = (const float*)d_in[3];    // [512]
  float* out = (float*)d_out;

  // workspace layout (bf16): xT | Wb | agg  -> 8 MB + 0.5 MB + 8 MB
  bf16_t* xT = (bf16_t*)d_ws;
  bf16_t* Wb = xT + (size_t)DIM * N_NODES;
  bf16_t* agg = Wb + (size_t)DIM * DIM;

  k_transpose_x<<<dim3(N_NODES / 64, DIM / 64), 256, 0, stream>>>(x, xT);
  k_cvt_w<<<dim3((DIM * DIM / 4) / 256), 256, 0, stream>>>(W, Wb);
  k_gemm1<<<dim3(DIM / 128, N_NODES / 128), 512, 0, stream>>>(adj, xT, agg);
  k_gemm2<<<dim3(DIM / 128, N_NODES / 128), 512, 0, stream>>>(agg, Wb, b, out);
}

// Round 2
// 517.398 us; speedup vs baseline: 1.1918x; 1.1918x over previous
//
#include <hip/hip_runtime.h>

typedef __bf16 bf16_t;
typedef bf16_t bf16x8 __attribute__((ext_vector_type(8)));
typedef bf16_t bf16x4 __attribute__((ext_vector_type(4)));
typedef float f32x4 __attribute__((ext_vector_type(4)));

#define N_NODES 8192
#define DIM 512

// ---- transpose + convert: x [8192,512] f32 -> xT [512,8192] bf16 ------------
__global__ __launch_bounds__(256) void k_transpose_x(const float* __restrict__ x,
                                                     bf16_t* __restrict__ xT) {
  __shared__ float tile[64][65];
  const int m0 = blockIdx.x * 64;
  const int n0 = blockIdx.y * 64;
  const int t = threadIdx.x;
  const int r = t >> 4;         // 0..15
  const int c = (t & 15) << 2;  // 0..60
#pragma unroll
  for (int i = 0; i < 4; ++i) {
    f32x4 v = *(const f32x4*)&x[(size_t)(m0 + r + i * 16) * DIM + n0 + c];
    tile[r + i * 16][c + 0] = v.x;
    tile[r + i * 16][c + 1] = v.y;
    tile[r + i * 16][c + 2] = v.z;
    tile[r + i * 16][c + 3] = v.w;
  }
  __syncthreads();
#pragma unroll
  for (int i = 0; i < 4; ++i) {
    const int rn = r + i * 16;
    bf16x4 o = {(bf16_t)tile[c + 0][rn], (bf16_t)tile[c + 1][rn],
                (bf16_t)tile[c + 2][rn], (bf16_t)tile[c + 3][rn]};
    *(bf16x4*)&xT[(size_t)(n0 + rn) * N_NODES + m0 + c] = o;
  }
}

// ---- convert W [512,512] f32 -> bf16 (layout already [n][k] for B^T) --------
__global__ __launch_bounds__(256) void k_cvt_w(const float* __restrict__ W,
                                               bf16_t* __restrict__ Wb) {
  const int t = blockIdx.x * 256 + threadIdx.x;
  f32x4 v = *(const f32x4*)&W[(size_t)t * 4];
  bf16x4 o = {(bf16_t)v.x, (bf16_t)v.y, (bf16_t)v.z, (bf16_t)v.w};
  *(bf16x4*)&Wb[(size_t)t * 4] = o;
}

// ---- GEMM: C[M,N] = A[M,K] @ B[N,K]^T  (optionally +bias, relu) -------------
// Tile 64x128, BK=64, 256 threads = 4 waves in 2x2 grid, wave-tile 32x64.
// Register-prefetch pipeline: global loads for iter k+1 issue before the MFMA
// phase of iter k, so HBM latency overlaps compute. Single LDS buffer.
// Grid is always 512 blocks (Mtiles=128 x Ntiles=4), XCD-swizzled so the 4
// N-tiles sharing A-rows land on the same XCD (blockIdx%8 ~ XCD).
template <bool A_F32, bool EPI_BIAS_RELU>
__global__ __launch_bounds__(256, 2) void k_gemm(const void* __restrict__ Av,
                                                 const bf16_t* __restrict__ B,
                                                 const float* __restrict__ bias,
                                                 void* __restrict__ Cv, int K) {
  constexpr int LDA = 72;  // 64+8 pad: 144B row stride -> 2-way banks (free)
  constexpr int LDB = 72;
  __shared__ bf16_t As[64 * LDA];
  __shared__ bf16_t Bs[128 * LDB];

  const int b = blockIdx.x;
  const int j8 = b & 7;         // ~XCD id
  const int kb = b >> 3;        // 0..63
  const int n_tile = kb & 3;    // 4 N-tiles consecutive-in-time on same XCD
  const int m_tile = (kb >> 2) * 8 + j8;  // 0..127
  const int m0 = m_tile * 64;
  const int n0 = n_tile * 128;

  const int t = threadIdx.x;
  const int lane = t & 63;
  const int w = t >> 6;
  const int wr = w & 1;   // wave row (32 rows)
  const int wc = w >> 1;  // wave col (64 cols)
  const int lrow = lane & 15;
  const int quad = lane >> 4;

  // staging coordinates
  const int ar = t >> 2, aq = t & 3;  // A: row 0..63, 16 elems at aq*16
  const int br = t >> 1, bq = t & 1;  // B: row 0..127, 32 elems at bq*32

  const float* apf = (const float*)Av + (size_t)(m0 + ar) * K + aq * 16;
  const bf16_t* apb = (const bf16_t*)Av + (size_t)(m0 + ar) * K + aq * 16;
  const bf16_t* bp = B + (size_t)(n0 + br) * K + bq * 32;
  bf16_t* aw = &As[ar * LDA + aq * 16];
  bf16_t* bw = &Bs[br * LDB + bq * 32];

  f32x4 apre[4];
  bf16x8 apreb[2];
  bf16x8 bpre[4];

  auto load_pre = [&](int k0) {
    if constexpr (A_F32) {
#pragma unroll
      for (int i = 0; i < 4; ++i) apre[i] = *(const f32x4*)(apf + k0 + i * 4);
    } else {
#pragma unroll
      for (int i = 0; i < 2; ++i) apreb[i] = *(const bf16x8*)(apb + k0 + i * 8);
    }
#pragma unroll
    for (int i = 0; i < 4; ++i) bpre[i] = *(const bf16x8*)(bp + k0 + i * 8);
  };

  load_pre(0);
  f32x4 acc[2][4] = {};

  for (int k0 = 0; k0 < K; k0 += 64) {
    bf16x8 a0{}, a1{};
    if constexpr (A_F32) {
#pragma unroll
      for (int i = 0; i < 4; ++i) {
        a0[i] = (bf16_t)apre[0][i];
        a0[i + 4] = (bf16_t)apre[1][i];
        a1[i] = (bf16_t)apre[2][i];
        a1[i + 4] = (bf16_t)apre[3][i];
      }
    } else {
      a0 = apreb[0];
      a1 = apreb[1];
    }
    bf16x8 b0 = bpre[0], b1 = bpre[1], b2 = bpre[2], b3 = bpre[3];
    __syncthreads();  // prior iter's ds_reads complete before overwrite
    *(bf16x8*)aw = a0;
    *(bf16x8*)(aw + 8) = a1;
    *(bf16x8*)bw = b0;
    *(bf16x8*)(bw + 8) = b1;
    *(bf16x8*)(bw + 16) = b2;
    *(bf16x8*)(bw + 24) = b3;
    __syncthreads();
    if (k0 + 64 < K) load_pre(k0 + 64);  // overlap next loads with MFMA phase
#pragma unroll
    for (int kk = 0; kk < 64; kk += 32) {
      bf16x8 af0 = *(const bf16x8*)&As[(wr * 32 + 0 + lrow) * LDA + kk + quad * 8];
      bf16x8 af1 = *(const bf16x8*)&As[(wr * 32 + 16 + lrow) * LDA + kk + quad * 8];
      bf16x8 bf0 = *(const bf16x8*)&Bs[(wc * 64 + 0 + lrow) * LDB + kk + quad * 8];
      bf16x8 bf1 = *(const bf16x8*)&Bs[(wc * 64 + 16 + lrow) * LDB + kk + quad * 8];
      bf16x8 bf2 = *(const bf16x8*)&Bs[(wc * 64 + 32 + lrow) * LDB + kk + quad * 8];
      bf16x8 bf3 = *(const bf16x8*)&Bs[(wc * 64 + 48 + lrow) * LDB + kk + quad * 8];
      acc[0][0] = __builtin_amdgcn_mfma_f32_16x16x32_bf16(af0, bf0, acc[0][0], 0, 0, 0);
      acc[0][1] = __builtin_amdgcn_mfma_f32_16x16x32_bf16(af0, bf1, acc[0][1], 0, 0, 0);
      acc[0][2] = __builtin_amdgcn_mfma_f32_16x16x32_bf16(af0, bf2, acc[0][2], 0, 0, 0);
      acc[0][3] = __builtin_amdgcn_mfma_f32_16x16x32_bf16(af0, bf3, acc[0][3], 0, 0, 0);
      acc[1][0] = __builtin_amdgcn_mfma_f32_16x16x32_bf16(af1, bf0, acc[1][0], 0, 0, 0);
      acc[1][1] = __builtin_amdgcn_mfma_f32_16x16x32_bf16(af1, bf1, acc[1][1], 0, 0, 0);
      acc[1][2] = __builtin_amdgcn_mfma_f32_16x16x32_bf16(af1, bf2, acc[1][2], 0, 0, 0);
      acc[1][3] = __builtin_amdgcn_mfma_f32_16x16x32_bf16(af1, bf3, acc[1][3], 0, 0, 0);
    }
  }

#pragma unroll
  for (int i = 0; i < 2; ++i)
#pragma unroll
    for (int j = 0; j < 4; ++j) {
      const int col = n0 + wc * 64 + j * 16 + lrow;
      float bj = 0.0f;
      if constexpr (EPI_BIAS_RELU) bj = bias[col];
#pragma unroll
      for (int r = 0; r < 4; ++r) {
        const int row = m0 + wr * 32 + i * 16 + quad * 4 + r;
        if constexpr (EPI_BIAS_RELU) {
          float v = acc[i][j][r] + bj;
          ((float*)Cv)[(size_t)row * DIM + col] = v > 0.0f ? v : 0.0f;
        } else {
          ((bf16_t*)Cv)[(size_t)row * DIM + col] = (bf16_t)acc[i][j][r];
        }
      }
    }
}

extern "C" void kernel_launch(void* const* d_in, const int* in_sizes, int n_in,
                              void* d_out, int out_size, void* d_ws, size_t ws_size,
                              hipStream_t stream) {
  const float* x = (const float*)d_in[0];    // [8192,512]
  const float* adj = (const float*)d_in[1];  // [8192,8192]
  const float* W = (const float*)d_in[2];    // [512,512]
  const float* b = (const float*)d_in[3];    // [512]
  float* out = (float*)d_out;

  bf16_t* xT = (bf16_t*)d_ws;                       // 8 MB
  bf16_t* Wb = xT + (size_t)DIM * N_NODES;          // 0.5 MB
  bf16_t* agg = Wb + (size_t)DIM * DIM;             // 8 MB

  k_transpose_x<<<dim3(N_NODES / 64, DIM / 64), 256, 0, stream>>>(x, xT);
  k_cvt_w<<<dim3((DIM * DIM / 4) / 256), 256, 0, stream>>>(W, Wb);
  k_gemm<true, false><<<dim3(512), 256, 0, stream>>>((const void*)adj, xT, nullptr,
                                                     (void*)agg, N_NODES);
  k_gemm<false, true><<<dim3(512), 256, 0, stream>>>((const void*)agg, Wb, b,
                                                     (void*)out, DIM);
}

// Round 3
// 508.071 us; speedup vs baseline: 1.2136x; 1.0184x over previous
//
#include <hip/hip_runtime.h>

typedef __bf16 bf16_t;
typedef bf16_t bf16x8 __attribute__((ext_vector_type(8)));
typedef bf16_t bf16x4 __attribute__((ext_vector_type(4)));
typedef float f32x4 __attribute__((ext_vector_type(4)));

#define N_NODES 8192
#define DIM 512

// ---- transpose + convert: x [8192,512] f32 -> xT [512,8192] bf16 ------------
__global__ __launch_bounds__(256) void k_transpose_x(const float* __restrict__ x,
                                                     bf16_t* __restrict__ xT) {
  __shared__ float tile[64][65];
  const int m0 = blockIdx.x * 64;
  const int n0 = blockIdx.y * 64;
  const int t = threadIdx.x;
  const int r = t >> 4;         // 0..15
  const int c = (t & 15) << 2;  // 0..60
#pragma unroll
  for (int i = 0; i < 4; ++i) {
    f32x4 v = *(const f32x4*)&x[(size_t)(m0 + r + i * 16) * DIM + n0 + c];
    tile[r + i * 16][c + 0] = v.x;
    tile[r + i * 16][c + 1] = v.y;
    tile[r + i * 16][c + 2] = v.z;
    tile[r + i * 16][c + 3] = v.w;
  }
  __syncthreads();
#pragma unroll
  for (int i = 0; i < 4; ++i) {
    const int rn = r + i * 16;
    bf16x4 o = {(bf16_t)tile[c + 0][rn], (bf16_t)tile[c + 1][rn],
                (bf16_t)tile[c + 2][rn], (bf16_t)tile[c + 3][rn]};
    *(bf16x4*)&xT[(size_t)(n0 + rn) * N_NODES + m0 + c] = o;
  }
}

// ---- convert W [512,512] f32 -> bf16 ---------------------------------------
__global__ __launch_bounds__(256) void k_cvt_w(const float* __restrict__ W,
                                               bf16_t* __restrict__ Wb) {
  const int t = blockIdx.x * 256 + threadIdx.x;
  f32x4 v = *(const f32x4*)&W[(size_t)t * 4];
  bf16x4 o = {(bf16_t)v.x, (bf16_t)v.y, (bf16_t)v.z, (bf16_t)v.w};
  *(bf16x4*)&Wb[(size_t)t * 4] = o;
}

// ---- GEMM1: P[s] = adj[:, s-chunk] @ xT[s-chunk, :]  (fp32 partials) --------
// 128x128 tile, BK=32, 512 thr = 8 waves (2x4), wave-tile 64x32.
// Double-buffered LDS (1 barrier/iter) + 2-deep register prefetch.
// Grid 256*S blocks, XCD-swizzled: same-M-band tiles grouped per XCD.
template <int S>
__global__ __launch_bounds__(512, 4) void k_gemm1(const float* __restrict__ A,
                                                  const bf16_t* __restrict__ Bt,
                                                  float* __restrict__ P) {
  constexpr int K = N_NODES;
  constexpr int KC = K / S;
  constexpr int NIT = KC / 32;
  constexpr int LD = 40;  // 32+8 pad, 80B stride
  __shared__ bf16_t As[2][128 * LD];
  __shared__ bf16_t Bs[2][128 * LD];

  const int b = blockIdx.x;
  const int xcd = b & 7;
  const int i6 = b >> 3;
  const int n_tile = i6 & 3;
  const int s = (i6 >> 2) & (S - 1);
  const int mg = (i6 >> 2) / S;
  const int m0 = (mg * 8 + xcd) * 128;
  const int n0 = n_tile * 128;

  const int t = threadIdx.x;
  const int lane = t & 63;
  const int w = t >> 6;
  const int wr = w & 1;   // wave row: 64 rows
  const int wc = w >> 1;  // wave col: 32 cols
  const int lrow = lane & 15;
  const int quad = lane >> 4;
  const int sr = t >> 2;  // staging row 0..127
  const int sq = t & 3;   // staging 8-elem group

  const float* ap = A + (size_t)(m0 + sr) * K + s * KC + sq * 8;
  const bf16_t* bp = Bt + (size_t)(n0 + sr) * K + s * KC + sq * 8;
  const int wofs = sr * LD + sq * 8;

  f32x4 pa0[2], pa1[2];
  bf16x8 pb[2];
  auto load_pre = [&](int k0, int sl) {
    pa0[sl] = *(const f32x4*)(ap + k0);
    pa1[sl] = *(const f32x4*)(ap + k0 + 4);
    pb[sl] = *(const bf16x8*)(bp + k0);
  };
  auto stage = [&](int sl, int buf) {
    bf16x8 av;
#pragma unroll
    for (int z = 0; z < 4; ++z) {
      av[z] = (bf16_t)pa0[sl][z];
      av[z + 4] = (bf16_t)pa1[sl][z];
    }
    *(bf16x8*)&As[buf][wofs] = av;
    *(bf16x8*)&Bs[buf][wofs] = pb[sl];
  };

  load_pre(0, 0);
  stage(0, 0);
  if (NIT > 1) load_pre(32, 1);
  f32x4 acc[4][2] = {};
  __syncthreads();

  int cur = 0;
#pragma unroll 2
  for (int it = 0; it < NIT; ++it) {
    if (it + 2 < NIT) load_pre((it + 2) * 32, it & 1);
    bf16x8 af[4], bfr[2];
#pragma unroll
    for (int ii = 0; ii < 4; ++ii)
      af[ii] = *(const bf16x8*)&As[cur][(wr * 64 + ii * 16 + lrow) * LD + quad * 8];
#pragma unroll
    for (int jj = 0; jj < 2; ++jj)
      bfr[jj] = *(const bf16x8*)&Bs[cur][(wc * 32 + jj * 16 + lrow) * LD + quad * 8];
#pragma unroll
    for (int ii = 0; ii < 4; ++ii)
#pragma unroll
      for (int jj = 0; jj < 2; ++jj)
        acc[ii][jj] = __builtin_amdgcn_mfma_f32_16x16x32_bf16(af[ii], bfr[jj], acc[ii][jj], 0, 0, 0);
    if (it + 1 < NIT) stage((it + 1) & 1, cur ^ 1);
    __syncthreads();
    cur ^= 1;
  }

  float* Pp = P + (size_t)s * N_NODES * DIM;
#pragma unroll
  for (int ii = 0; ii < 4; ++ii)
#pragma unroll
    for (int jj = 0; jj < 2; ++jj) {
      const int col = n0 + wc * 32 + jj * 16 + lrow;
#pragma unroll
      for (int r = 0; r < 4; ++r) {
        const int row = m0 + wr * 64 + ii * 16 + quad * 4 + r;
        Pp[(size_t)row * DIM + col] = acc[ii][jj][r];
      }
    }
}

// ---- GEMM2: out = relu((sum_s P[s]) @ W^T + b), fp32 out --------------------
// 64x128 tile, BK=64, 256 thr = 4 waves (2x2), wave-tile 32x64. K=512 only.
template <int S>
__global__ __launch_bounds__(256, 2) void k_gemm2(const float* __restrict__ P,
                                                  const bf16_t* __restrict__ Bw,
                                                  const float* __restrict__ bias,
                                                  float* __restrict__ out) {
  constexpr int K = DIM;
  constexpr int LDA = 72;
  constexpr int LDB = 72;
  constexpr size_t PS = (size_t)N_NODES * DIM;
  __shared__ bf16_t As[64 * LDA];
  __shared__ bf16_t Bs[128 * LDB];

  const int b = blockIdx.x;
  const int n0 = (b & 3) * 128;
  const int m0 = (b >> 2) * 64;
  const int t = threadIdx.x;
  const int lane = t & 63;
  const int w = t >> 6;
  const int wr = w & 1;
  const int wc = w >> 1;
  const int lrow = lane & 15;
  const int quad = lane >> 4;
  const int ar = t >> 2, aq = t & 3;  // A: 64 rows, 16 f32 at aq*16
  const int br = t >> 1, bq = t & 1;  // B: 128 rows, 32 bf16 at bq*32

  const float* ap = P + (size_t)(m0 + ar) * K + aq * 16;
  const bf16_t* bp = Bw + (size_t)(n0 + br) * K + bq * 32;
  bf16_t* aw = &As[ar * LDA + aq * 16];
  bf16_t* bw = &Bs[br * LDB + bq * 32];

  f32x4 acc[2][4] = {};

  for (int k0 = 0; k0 < K; k0 += 64) {
    f32x4 av[4];
#pragma unroll
    for (int z = 0; z < 4; ++z) av[z] = *(const f32x4*)(ap + k0 + z * 4);
#pragma unroll
    for (int s2 = 1; s2 < S; ++s2)
#pragma unroll
      for (int z = 0; z < 4; ++z) av[z] += *(const f32x4*)(ap + s2 * PS + k0 + z * 4);
    bf16x8 b0 = *(const bf16x8*)(bp + k0);
    bf16x8 b1 = *(const bf16x8*)(bp + k0 + 8);
    bf16x8 b2 = *(const bf16x8*)(bp + k0 + 16);
    bf16x8 b3 = *(const bf16x8*)(bp + k0 + 24);
    bf16x8 a0, a1;
#pragma unroll
    for (int z = 0; z < 4; ++z) {
      a0[z] = (bf16_t)av[0][z];
      a0[z + 4] = (bf16_t)av[1][z];
      a1[z] = (bf16_t)av[2][z];
      a1[z + 4] = (bf16_t)av[3][z];
    }
    __syncthreads();
    *(bf16x8*)aw = a0;
    *(bf16x8*)(aw + 8) = a1;
    *(bf16x8*)bw = b0;
    *(bf16x8*)(bw + 8) = b1;
    *(bf16x8*)(bw + 16) = b2;
    *(bf16x8*)(bw + 24) = b3;
    __syncthreads();
#pragma unroll
    for (int kk = 0; kk < 64; kk += 32) {
      bf16x8 af0 = *(const bf16x8*)&As[(wr * 32 + 0 + lrow) * LDA + kk + quad * 8];
      bf16x8 af1 = *(const bf16x8*)&As[(wr * 32 + 16 + lrow) * LDA + kk + quad * 8];
      bf16x8 bf0 = *(const bf16x8*)&Bs[(wc * 64 + 0 + lrow) * LDB + kk + quad * 8];
      bf16x8 bf1 = *(const bf16x8*)&Bs[(wc * 64 + 16 + lrow) * LDB + kk + quad * 8];
      bf16x8 bf2 = *(const bf16x8*)&Bs[(wc * 64 + 32 + lrow) * LDB + kk + quad * 8];
      bf16x8 bf3 = *(const bf16x8*)&Bs[(wc * 64 + 48 + lrow) * LDB + kk + quad * 8];
      acc[0][0] = __builtin_amdgcn_mfma_f32_16x16x32_bf16(af0, bf0, acc[0][0], 0, 0, 0);
      acc[0][1] = __builtin_amdgcn_mfma_f32_16x16x32_bf16(af0, bf1, acc[0][1], 0, 0, 0);
      acc[0][2] = __builtin_amdgcn_mfma_f32_16x16x32_bf16(af0, bf2, acc[0][2], 0, 0, 0);
      acc[0][3] = __builtin_amdgcn_mfma_f32_16x16x32_bf16(af0, bf3, acc[0][3], 0, 0, 0);
      acc[1][0] = __builtin_amdgcn_mfma_f32_16x16x32_bf16(af1, bf0, acc[1][0], 0, 0, 0);
      acc[1][1] = __builtin_amdgcn_mfma_f32_16x16x32_bf16(af1, bf1, acc[1][1], 0, 0, 0);
      acc[1][2] = __builtin_amdgcn_mfma_f32_16x16x32_bf16(af1, bf2, acc[1][2], 0, 0, 0);
      acc[1][3] = __builtin_amdgcn_mfma_f32_16x16x32_bf16(af1, bf3, acc[1][3], 0, 0, 0);
    }
  }

#pragma unroll
  for (int i = 0; i < 2; ++i)
#pragma unroll
    for (int j = 0; j < 4; ++j) {
      const int col = n0 + wc * 64 + j * 16 + lrow;
      const float bj = bias[col];
#pragma unroll
      for (int r = 0; r < 4; ++r) {
        const int row = m0 + wr * 32 + i * 16 + quad * 4 + r;
        float v = acc[i][j][r] + bj;
        out[(size_t)row * DIM + col] = v > 0.0f ? v : 0.0f;
      }
    }
}

extern "C" void kernel_launch(void* const* d_in, const int* in_sizes, int n_in,
                              void* d_out, int out_size, void* d_ws, size_t ws_size,
                              hipStream_t stream) {
  const float* x = (const float*)d_in[0];    // [8192,512]
  const float* adj = (const float*)d_in[1];  // [8192,8192]
  const float* W = (const float*)d_in[2];    // [512,512]
  const float* b = (const float*)d_in[3];    // [512]
  float* out = (float*)d_out;

  // ws layout: xT (8 MB bf16) | Wb (0.5 MB bf16) | P (S x 16 MB f32)
  bf16_t* xT = (bf16_t*)d_ws;
  bf16_t* Wb = xT + (size_t)DIM * N_NODES;
  float* P = (float*)(Wb + (size_t)DIM * DIM);
  const size_t base = (size_t)DIM * N_NODES * 2 + (size_t)DIM * DIM * 2;
  const size_t pslab = (size_t)N_NODES * DIM * 4;

  k_transpose_x<<<dim3(N_NODES / 64, DIM / 64), 256, 0, stream>>>(x, xT);
  k_cvt_w<<<dim3((DIM * DIM / 4) / 256), 256, 0, stream>>>(W, Wb);

  if (ws_size >= base + 4 * pslab) {
    k_gemm1<4><<<dim3(256 * 4), 512, 0, stream>>>(adj, xT, P);
    k_gemm2<4><<<dim3(512), 256, 0, stream>>>(P, Wb, b, out);
  } else {
    k_gemm1<1><<<dim3(256), 512, 0, stream>>>(adj, xT, P);
    k_gemm2<1><<<dim3(512), 256, 0, stream>>>(P, Wb, b, out);
  }
}